// Round 11
// baseline (196.893 us; speedup 1.0000x reference)
//
#include <hip/hip_runtime.h>

#define NN 1024
#define DD 128
#define NBLK 256

typedef __attribute__((ext_vector_type(4))) float f32x4;

// Device-scope (IC write-through) store, bit-cast via unsigned for safe ISel.
__device__ __forceinline__ void scstore(float* p, float v) {
    __hip_atomic_store((unsigned*)p, __float_as_uint(v),
                       __ATOMIC_RELAXED, __HIP_MEMORY_SCOPE_AGENT);
}

// Fence-free grid barrier (256 blocks) — PROVEN r9 protocol (95us kernel, passed).
// Residency hardening (r10 lesson): LDS<=78KB + VGPR<=64 give 2-blocks/CU capacity,
// so all 256 blocks are co-resident even if a CU is partially occupied at dispatch.
__device__ __forceinline__ void gridbar(unsigned* bar, unsigned ep) {
    __syncthreads();
    if (threadIdx.x == 0) {
        asm volatile("s_waitcnt vmcnt(0)" ::: "memory");
        unsigned old = __hip_atomic_fetch_add(&bar[(blockIdx.x & 15) << 5], 1u,
                                              __ATOMIC_RELAXED, __HIP_MEMORY_SCOPE_AGENT);
        if (old == (ep << 4) - 1) {
            unsigned mold = __hip_atomic_fetch_add(&bar[512], 1u,
                                                   __ATOMIC_RELAXED, __HIP_MEMORY_SCOPE_AGENT);
            if (mold == (ep << 4) - 1)
                __hip_atomic_store(&bar[544], ep, __ATOMIC_RELAXED, __HIP_MEMORY_SCOPE_AGENT);
        }
        while (__hip_atomic_load(&bar[544], __ATOMIC_RELAXED, __HIP_MEMORY_SCOPE_AGENT) < ep)
            __builtin_amdgcn_s_sleep(4);
    }
    __syncthreads();
}

// Column-GEMM with 2 independent acc chains (r7-proven): 8 W-loads in flight per iter.
__device__ __forceinline__ float dotW2(const float* __restrict__ W, const float* x, int d) {
    float a0 = 0.f, a1 = 0.f;
#pragma unroll 2
    for (int k = 0; k < DD; k += 8) {
        f32x4 xa = *(const f32x4*)(x + k);       // wave-uniform LDS broadcast (free)
        f32x4 xb = *(const f32x4*)(x + k + 4);
        a0 = fmaf(xa[0], W[(k + 0) * DD + d], a0);
        a0 = fmaf(xa[1], W[(k + 1) * DD + d], a0);
        a0 = fmaf(xa[2], W[(k + 2) * DD + d], a0);
        a0 = fmaf(xa[3], W[(k + 3) * DD + d], a0);
        a1 = fmaf(xb[0], W[(k + 4) * DD + d], a1);
        a1 = fmaf(xb[1], W[(k + 5) * DD + d], a1);
        a1 = fmaf(xb[2], W[(k + 6) * DD + d], a1);
        a1 = fmaf(xb[3], W[(k + 7) * DD + d], a1);
    }
    return a0 + a1;
}

__global__ __launch_bounds__(1024, 8) void k_fused(   // 8 waves/EU => VGPR<=64 => 2 blocks/CU
    const float* __restrict__ adj, const float* __restrict__ ew,
    const float* __restrict__ nf, const float* __restrict__ We, const float* __restrict__ be,
    const float* __restrict__ Wu, const float* __restrict__ bu,
    const float* __restrict__ Wv, const float* __restrict__ bv,
    const float* __restrict__ Wg, const float* __restrict__ bg,
    const float* __restrict__ Wc1, const float* __restrict__ bc1,
    const float* __restrict__ Wc2, const float* __restrict__ bc2,
    float* __restrict__ vA, float* __restrict__ vB, float* __restrict__ vC,
    float* __restrict__ hi, float* __restrict__ hj,
    float* __restrict__ S1, float* __restrict__ S2,
    float* __restrict__ lossAcc, unsigned* __restrict__ counter,
    unsigned* __restrict__ barCnt, float* __restrict__ outL)
{
    __shared__ float hS[4][DD], uS[4][DD], aggS[4][DD];     // 6KB
    __shared__ float gg[2][4][DD];                          // 4KB
    __shared__ float sred[2][4][2];
    __shared__ float wS[DD];
    __shared__ union {
        struct { float adjS[4][NN]; float pS[16][4][DD]; } g;              // 16+32 = 48KB
        struct { float hiS[64][132]; float hjS[64][130]; float lred[16]; } e;  // 67.1KB
    } sm;   // union 67.1KB; kernel total ~77.9KB <= 80KB => 2 blocks/CU LDS capacity

    int tid = threadIdx.x, bx = blockIdx.x;
    int row0 = bx * 4;
    int halfq = tid >> 9, rq = (tid >> 7) & 3, d = tid & 127;
    unsigned ep = 0;

    // ---------------- Phase 0: stage adj rows + embed + layer-0 u/v ----------------
    {
        int r = tid >> 8, k0 = (tid & 255) << 2;
        *(f32x4*)&sm.g.adjS[r][k0] = *(const f32x4*)(adj + (size_t)(row0 + r) * NN + k0);
    }
    if (tid < 512) {
        int r = tid >> 7;
        float a = be[d];
#pragma unroll
        for (int k = 0; k < 3; ++k) a = fmaf(nf[(row0 + r) * 3 + k], We[k * DD + d], a);
        hS[r][d] = a;
    }
    __syncthreads();
    {
        float acc = dotW2(halfq ? Wv : Wu, hS[rq], d);
        if (!halfq) uS[rq][d] = acc + bu[d];
        else        scstore(&vA[(size_t)(row0 + rq) * DD + d], acc + bv[d]);
    }
    gridbar(barCnt, ++ep);

    // ---------------- 3 GCN layers: one barrier each ----------------
    for (int l = 0; l < 3; ++l) {
        const float* vin = (l == 0) ? vA : (l == 1) ? vB : vC;
        float* vout = (l == 0) ? vB : vC;                      // unused at l==2

        // agg partials: 32 k-chunks x 32 d-quads (r9-proven body); two-phase pS write
        // (chunks 16..31 write, sync, chunks 0..15 add) halves pS LDS to 32KB.
        {
            int kk = tid >> 5, dq = tid & 31;
            int d0 = dq << 2, kb = kk << 5;
            f32x4 ac0 = {0.f,0.f,0.f,0.f}, ac1 = ac0, ac2 = ac0, ac3 = ac0;
#pragma unroll 2
            for (int ku = 0; ku < 32; ku += 4) {
                f32x4 a0 = *(const f32x4*)&sm.g.adjS[0][kb + ku];
                f32x4 a1 = *(const f32x4*)&sm.g.adjS[1][kb + ku];
                f32x4 a2 = *(const f32x4*)&sm.g.adjS[2][kb + ku];
                f32x4 a3 = *(const f32x4*)&sm.g.adjS[3][kb + ku];
#pragma unroll
                for (int j = 0; j < 4; ++j) {
                    f32x4 v4 = *(const f32x4*)(vin + (size_t)(kb + ku + j) * DD + d0);
#pragma unroll
                    for (int c = 0; c < 4; ++c) {
                        ac0[c] = fmaf(a0[j], v4[c], ac0[c]);
                        ac1[c] = fmaf(a1[j], v4[c], ac1[c]);
                        ac2[c] = fmaf(a2[j], v4[c], ac2[c]);
                        ac3[c] = fmaf(a3[j], v4[c], ac3[c]);
                    }
                }
            }
            if (kk >= 16) {
                int ks = kk - 16;
                *(f32x4*)&sm.g.pS[ks][0][d0] = ac0;
                *(f32x4*)&sm.g.pS[ks][1][d0] = ac1;
                *(f32x4*)&sm.g.pS[ks][2][d0] = ac2;
                *(f32x4*)&sm.g.pS[ks][3][d0] = ac3;
            }
            __syncthreads();
            if (kk < 16) {
                f32x4 p0 = *(const f32x4*)&sm.g.pS[kk][0][d0];
                f32x4 p1 = *(const f32x4*)&sm.g.pS[kk][1][d0];
                f32x4 p2 = *(const f32x4*)&sm.g.pS[kk][2][d0];
                f32x4 p3 = *(const f32x4*)&sm.g.pS[kk][3][d0];
#pragma unroll
                for (int c = 0; c < 4; ++c) {
                    p0[c] += ac0[c]; p1[c] += ac1[c]; p2[c] += ac2[c]; p3[c] += ac3[c];
                }
                *(f32x4*)&sm.g.pS[kk][0][d0] = p0;
                *(f32x4*)&sm.g.pS[kk][1][d0] = p1;
                *(f32x4*)&sm.g.pS[kk][2][d0] = p2;
                *(f32x4*)&sm.g.pS[kk][3][d0] = p3;
            }
        }
        __syncthreads();
        if (tid < 512) {
            int r = tid >> 7;
            float s = 0.f;
#pragma unroll
            for (int c = 0; c < 16; ++c) s += sm.g.pS[c][r][d];
            aggS[r][d] = s;
        }
        __syncthreads();
        // gate halves: gg[0] = u @ WgA, gg[1] = agg @ WgB
        {
            const float* W = Wg + l * (2 * DD * DD) + (halfq ? DD * DD : 0);
            gg[halfq][rq][d] = dotW2(W, halfq ? aggS[rq] : uS[rq], d);
        }
        __syncthreads();
        if (tid < 512) {
            int r = tid >> 7;
            float g = 1.f / (1.f + __expf(-(gg[0][r][d] + gg[1][r][d] + bg[l * DD + d])));
            float nh = fmaf(g, aggS[r][d], hS[r][d]);
            hS[r][d] = nh > 0.f ? nh : 0.f;
        }
        __syncthreads();
        // next-layer u/v GEMM, or classifier head at l==2
        {
            const float* W2 = (l < 2) ? ((halfq ? Wv : Wu) + (l + 1) * DD * DD)
                                      : (Wc1 + (halfq ? DD * DD : 0));
            float acc = dotW2(W2, hS[rq], d);
            if (l < 2) {
                if (!halfq) uS[rq][d] = acc + bu[(l + 1) * DD + d];
                else        scstore(&vout[(size_t)(row0 + rq) * DD + d], acc + bv[(l + 1) * DD + d]);
            } else {
                float val = acc + (halfq ? 0.f : bc1[d]);
                scstore(&(halfq ? hj : hi)[(size_t)(row0 + rq) * DD + d], val);
                float p = val * Wc2[d];
#pragma unroll
                for (int off = 32; off; off >>= 1) p += __shfl_down(p, off);
                if ((tid & 63) == 0) sred[halfq][rq][(tid >> 6) & 1] = p;
            }
        }
        if (l == 2) {
            __syncthreads();
            if (tid < 4) scstore(&S1[row0 + tid], sred[0][tid][0] + sred[0][tid][1]);
            else if (tid < 8) scstore(&S2[row0 + tid - 4], sred[1][tid - 4][0] + sred[1][tid - 4][1]);
        }
        gridbar(barCnt, ++ep);
    }

    // ---------------- edge classifier: one 64x64 tile per block + loss ----------------
    // T14: adj/ew (HBM) + S1/S2 (IC) loads issued BEFORE staging/compute.
    {
        int i0 = (bx >> 4) << 6, j0 = (bx & 15) << 6;
        int ty = tid >> 5, tx = tid & 31;
        int ia = i0 + ty, ib = ia + 32, ja = j0 + tx, jb = ja + 32;
        size_t o00 = (size_t)ia * NN + ja, o01 = o00 + 32;
        size_t o10 = (size_t)ib * NN + ja, o11 = o10 + 32;
        float av00 = adj[o00], av01 = adj[o01], av10 = adj[o10], av11 = adj[o11];
        float ev00 = ew[o00],  ev01 = ew[o01],  ev10 = ew[o10],  ev11 = ew[o11];
        float s1a = S1[ia], s1b = S1[ib], s2a = S2[ja], s2b = S2[jb];
        if (tid < 128) wS[tid] = Wc2[tid];
        for (int e2 = tid; e2 < 2048; e2 += 1024) {
            int r = e2 >> 5, c = (e2 & 31) << 2;
            *(f32x4*)&sm.e.hiS[r][c] = *(const f32x4*)(hi + (size_t)(i0 + r) * DD + c);
            f32x4 jv = *(const f32x4*)(hj + (size_t)(j0 + r) * DD + c);
            float2 j01; j01.x = jv[0]; j01.y = jv[1];
            float2 j23; j23.x = jv[2]; j23.y = jv[3];
            *(float2*)&sm.e.hjS[r][c] = j01;
            *(float2*)&sm.e.hjS[r][c + 2] = j23;
        }
        __syncthreads();
        float a00 = 0.f, a01 = 0.f, a10 = 0.f, a11 = 0.f;
#pragma unroll 4
        for (int hh = 0; hh < DD; hh += 4) {
            f32x4 x0 = *(const f32x4*)&sm.e.hiS[ty][hh];
            f32x4 x1 = *(const f32x4*)&sm.e.hiS[ty + 32][hh];
            float2 y0a = *(const float2*)&sm.e.hjS[tx][hh];
            float2 y0b = *(const float2*)&sm.e.hjS[tx][hh + 2];
            float2 y1a = *(const float2*)&sm.e.hjS[tx + 32][hh];
            float2 y1b = *(const float2*)&sm.e.hjS[tx + 32][hh + 2];
            f32x4 w4 = *(const f32x4*)&wS[hh];
            a00 = fmaf(fabsf(x0[0] + y0a.x), w4[0], a00);
            a00 = fmaf(fabsf(x0[1] + y0a.y), w4[1], a00);
            a00 = fmaf(fabsf(x0[2] + y0b.x), w4[2], a00);
            a00 = fmaf(fabsf(x0[3] + y0b.y), w4[3], a00);
            a01 = fmaf(fabsf(x0[0] + y1a.x), w4[0], a01);
            a01 = fmaf(fabsf(x0[1] + y1a.y), w4[1], a01);
            a01 = fmaf(fabsf(x0[2] + y1b.x), w4[2], a01);
            a01 = fmaf(fabsf(x0[3] + y1b.y), w4[3], a01);
            a10 = fmaf(fabsf(x1[0] + y0a.x), w4[0], a10);
            a10 = fmaf(fabsf(x1[1] + y0a.y), w4[1], a10);
            a10 = fmaf(fabsf(x1[2] + y0b.x), w4[2], a10);
            a10 = fmaf(fabsf(x1[3] + y0b.y), w4[3], a10);
            a11 = fmaf(fabsf(x1[0] + y1a.x), w4[0], a11);
            a11 = fmaf(fabsf(x1[1] + y1a.y), w4[1], a11);
            a11 = fmaf(fabsf(x1[2] + y1b.x), w4[2], a11);
            a11 = fmaf(fabsf(x1[3] + y1b.y), w4[3], a11);
        }
        float bcv = bc2[0];
        float lg00 = fmaf(0.5f, a00 + s1a + s2a, bcv);
        float lg01 = fmaf(0.5f, a01 + s1a + s2b, bcv);
        float lg10 = fmaf(0.5f, a10 + s1b + s2a, bcv);
        float lg11 = fmaf(0.5f, a11 + s1b + s2b, bcv);
        outL[o00] = lg00; outL[o01] = lg01; outL[o10] = lg10; outL[o11] = lg11;
        float t0 = fmaf(lg00, av00, -ev00);
        float t1 = fmaf(lg01, av01, -ev01);
        float t2 = fmaf(lg10, av10, -ev10);
        float t3 = fmaf(lg11, av11, -ev11);
        float ls = fmaf(t0, t0, fmaf(t1, t1, fmaf(t2, t2, t3 * t3)));
#pragma unroll
        for (int off = 32; off; off >>= 1) ls += __shfl_down(ls, off);
        if ((tid & 63) == 0) sm.e.lred[tid >> 6] = ls;
        __syncthreads();
        if (tid == 0) {
            float bls = 0.f;
#pragma unroll
            for (int w = 0; w < 16; ++w) bls += sm.e.lred[w];
            atomicAdd(lossAcc, bls);
            asm volatile("s_waitcnt vmcnt(0)" ::: "memory");
            unsigned old = atomicAdd(counter, 1u);
            if (old == NBLK - 1u) {
                unsigned Lb = __hip_atomic_load((unsigned*)lossAcc,
                                                __ATOMIC_RELAXED, __HIP_MEMORY_SCOPE_AGENT);
                outL[(size_t)NN * NN] = __uint_as_float(Lb) * (1.f / (1024.f * 1024.f));
            }
        }
    }
}

extern "C" void kernel_launch(void* const* d_in, const int* in_sizes, int n_in,
                              void* d_out, int out_size, void* d_ws, size_t ws_size,
                              hipStream_t stream)
{
    const float* nf  = (const float*)d_in[0];
    const float* adj = (const float*)d_in[1];
    const float* ew  = (const float*)d_in[2];
    const float* We  = (const float*)d_in[3];
    const float* be  = (const float*)d_in[4];
    const float* Wu  = (const float*)d_in[5];
    const float* bu  = (const float*)d_in[6];
    const float* Wv  = (const float*)d_in[7];
    const float* bv  = (const float*)d_in[8];
    const float* Wg  = (const float*)d_in[9];
    const float* bg  = (const float*)d_in[10];
    const float* Wc1 = (const float*)d_in[11];
    const float* bc1 = (const float*)d_in[12];
    const float* Wc2 = (const float*)d_in[13];
    const float* bc2 = (const float*)d_in[14];

    float* ws = (float*)d_ws;
    float* vA  = ws;                                 // 131072  (write-once: phase0)
    float* vB  = ws + 131072;                        // 131072  (write-once: layer0)
    float* vC  = ws + 262144;                        // 131072  (write-once: layer1)
    float* hi  = ws + 393216;                        // 131072  (write-once: layer2)
    float* hj  = ws + 524288;                        // 131072  (write-once: layer2)
    float* S1  = ws + 655360;                        // 1024
    float* S2  = ws + 656384;                        // 1024
    float* lossAcc = ws + 657408;                    // 1
    unsigned* counter = (unsigned*)(ws + 657409);    // 1
    unsigned* barCnt = (unsigned*)(ws + 657440);     // 545 uints (sub/master/flag)

    // zero lossAcc + counter + barrier state (capture-legal)
    hipMemsetAsync((void*)lossAcc, 0, 2560, stream);
    k_fused<<<NBLK, 1024, 0, stream>>>(adj, ew, nf, We, be, Wu, bu, Wv, bv, Wg, bg,
                                       Wc1, bc1, Wc2, bc2, vA, vB, vC, hi, hj, S1, S2,
                                       lossAcc, counter, barCnt, (float*)d_out);
}

// Round 12
// 172.343 us; speedup vs baseline: 1.1425x; 1.1425x over previous
//
#include <hip/hip_runtime.h>

#define NN 1024
#define DD 128
#define NBLK 256

typedef __attribute__((ext_vector_type(4))) float f32x4;

// Device-scope (IC write-through) store, bit-cast via unsigned for safe ISel.
__device__ __forceinline__ void scstore(float* p, float v) {
    __hip_atomic_store((unsigned*)p, __float_as_uint(v),
                       __ATOMIC_RELAXED, __HIP_MEMORY_SCOPE_AGENT);
}

// Fence-free grid barrier (256 blocks) — PROVEN r9 protocol (95us kernel, passed).
// Residency hardening: LDS 78.3KB (2 blocks/CU) + natural VGPR<=64 (8 waves/EU).
// NO launch_bounds squeeze (r11 lesson: forcing min-waves=8 drove VGPR to 32 and
// spilled ~55MB of scratch traffic to HBM).
__device__ __forceinline__ void gridbar(unsigned* bar, unsigned ep) {
    __syncthreads();
    if (threadIdx.x == 0) {
        asm volatile("s_waitcnt vmcnt(0)" ::: "memory");
        unsigned old = __hip_atomic_fetch_add(&bar[(blockIdx.x & 15) << 5], 1u,
                                              __ATOMIC_RELAXED, __HIP_MEMORY_SCOPE_AGENT);
        if (old == (ep << 4) - 1) {
            unsigned mold = __hip_atomic_fetch_add(&bar[512], 1u,
                                                   __ATOMIC_RELAXED, __HIP_MEMORY_SCOPE_AGENT);
            if (mold == (ep << 4) - 1)
                __hip_atomic_store(&bar[544], ep, __ATOMIC_RELAXED, __HIP_MEMORY_SCOPE_AGENT);
        }
        while (__hip_atomic_load(&bar[544], __ATOMIC_RELAXED, __HIP_MEMORY_SCOPE_AGENT) < ep)
            __builtin_amdgcn_s_sleep(4);
    }
    __syncthreads();
}

// Column-GEMM with 2 independent acc chains (r7-proven): 8 W-loads in flight per iter.
__device__ __forceinline__ float dotW2(const float* __restrict__ W, const float* x, int d) {
    float a0 = 0.f, a1 = 0.f;
#pragma unroll 2
    for (int k = 0; k < DD; k += 8) {
        f32x4 xa = *(const f32x4*)(x + k);       // wave-uniform LDS broadcast (free)
        f32x4 xb = *(const f32x4*)(x + k + 4);
        a0 = fmaf(xa[0], W[(k + 0) * DD + d], a0);
        a0 = fmaf(xa[1], W[(k + 1) * DD + d], a0);
        a0 = fmaf(xa[2], W[(k + 2) * DD + d], a0);
        a0 = fmaf(xa[3], W[(k + 3) * DD + d], a0);
        a1 = fmaf(xb[0], W[(k + 4) * DD + d], a1);
        a1 = fmaf(xb[1], W[(k + 5) * DD + d], a1);
        a1 = fmaf(xb[2], W[(k + 6) * DD + d], a1);
        a1 = fmaf(xb[3], W[(k + 7) * DD + d], a1);
    }
    return a0 + a1;
}

__global__ __launch_bounds__(1024, 4) void k_fused(   // r9-proven regime: natural VGPR ~52
    const float* __restrict__ adj, const float* __restrict__ ew,
    const float* __restrict__ nf, const float* __restrict__ We, const float* __restrict__ be,
    const float* __restrict__ Wu, const float* __restrict__ bu,
    const float* __restrict__ Wv, const float* __restrict__ bv,
    const float* __restrict__ Wg, const float* __restrict__ bg,
    const float* __restrict__ Wc1, const float* __restrict__ bc1,
    const float* __restrict__ Wc2, const float* __restrict__ bc2,
    float* __restrict__ vA, float* __restrict__ vB, float* __restrict__ vC,
    float* __restrict__ hi, float* __restrict__ hj,
    float* __restrict__ S1, float* __restrict__ S2,
    float* __restrict__ lossAcc, unsigned* __restrict__ counter,
    unsigned* __restrict__ barCnt, float* __restrict__ outL)
{
    __shared__ float hS[4][DD], uS[4][DD], aggS[4][DD];     // 6KB
    __shared__ float gg[2][4][DD];                          // 4KB
    __shared__ float sred[2][4][2];
    __shared__ float wS[DD];
    __shared__ union {
        struct { float adjS[4][NN]; float pS[16][4][DD]; } g;              // 16+32 = 48KB
        struct { float hiS[64][132]; float hjS[64][130]; float lred[16]; } e;  // 65.6KB
    } sm;   // kernel total ~78.3KB => 2 blocks/CU LDS capacity (residency slack)

    int tid = threadIdx.x, bx = blockIdx.x;
    int row0 = bx * 4;
    int halfq = tid >> 9, rq = (tid >> 7) & 3, d = tid & 127;
    unsigned ep = 0;

    // ---------------- Phase 0: stage adj rows + embed + layer-0 u/v ----------------
    {
        int r = tid >> 8, k0 = (tid & 255) << 2;
        *(f32x4*)&sm.g.adjS[r][k0] = *(const f32x4*)(adj + (size_t)(row0 + r) * NN + k0);
    }
    if (tid < 512) {
        int r = tid >> 7;
        float a = be[d];
#pragma unroll
        for (int k = 0; k < 3; ++k) a = fmaf(nf[(row0 + r) * 3 + k], We[k * DD + d], a);
        hS[r][d] = a;
    }
    __syncthreads();
    {
        float acc = dotW2(halfq ? Wv : Wu, hS[rq], d);
        if (!halfq) uS[rq][d] = acc + bu[d];
        else        scstore(&vA[(size_t)(row0 + rq) * DD + d], acc + bv[d]);
    }
    gridbar(barCnt, ++ep);

    // ---------------- 3 GCN layers: one barrier each ----------------
    for (int l = 0; l < 3; ++l) {
        const float* vin = (l == 0) ? vA : (l == 1) ? vB : vC;
        float* vout = (l == 0) ? vB : vC;                      // unused at l==2

        // agg partials: 32 k-chunks x 32 d-quads (r9-proven body); two-phase pS write
        // (chunks 16..31 write, sync, chunks 0..15 add) halves pS LDS to 32KB.
        {
            int kk = tid >> 5, dq = tid & 31;
            int d0 = dq << 2, kb = kk << 5;
            f32x4 ac0 = {0.f,0.f,0.f,0.f}, ac1 = ac0, ac2 = ac0, ac3 = ac0;
#pragma unroll 2
            for (int ku = 0; ku < 32; ku += 4) {
                f32x4 a0 = *(const f32x4*)&sm.g.adjS[0][kb + ku];
                f32x4 a1 = *(const f32x4*)&sm.g.adjS[1][kb + ku];
                f32x4 a2 = *(const f32x4*)&sm.g.adjS[2][kb + ku];
                f32x4 a3 = *(const f32x4*)&sm.g.adjS[3][kb + ku];
#pragma unroll
                for (int j = 0; j < 4; ++j) {
                    f32x4 v4 = *(const f32x4*)(vin + (size_t)(kb + ku + j) * DD + d0);
#pragma unroll
                    for (int c = 0; c < 4; ++c) {
                        ac0[c] = fmaf(a0[j], v4[c], ac0[c]);
                        ac1[c] = fmaf(a1[j], v4[c], ac1[c]);
                        ac2[c] = fmaf(a2[j], v4[c], ac2[c]);
                        ac3[c] = fmaf(a3[j], v4[c], ac3[c]);
                    }
                }
            }
            if (kk >= 16) {
                int ks = kk - 16;
                *(f32x4*)&sm.g.pS[ks][0][d0] = ac0;
                *(f32x4*)&sm.g.pS[ks][1][d0] = ac1;
                *(f32x4*)&sm.g.pS[ks][2][d0] = ac2;
                *(f32x4*)&sm.g.pS[ks][3][d0] = ac3;
            }
            __syncthreads();
            if (kk < 16) {
                f32x4 p0 = *(const f32x4*)&sm.g.pS[kk][0][d0];
                f32x4 p1 = *(const f32x4*)&sm.g.pS[kk][1][d0];
                f32x4 p2 = *(const f32x4*)&sm.g.pS[kk][2][d0];
                f32x4 p3 = *(const f32x4*)&sm.g.pS[kk][3][d0];
#pragma unroll
                for (int c = 0; c < 4; ++c) {
                    p0[c] += ac0[c]; p1[c] += ac1[c]; p2[c] += ac2[c]; p3[c] += ac3[c];
                }
                *(f32x4*)&sm.g.pS[kk][0][d0] = p0;
                *(f32x4*)&sm.g.pS[kk][1][d0] = p1;
                *(f32x4*)&sm.g.pS[kk][2][d0] = p2;
                *(f32x4*)&sm.g.pS[kk][3][d0] = p3;
            }
        }
        __syncthreads();
        if (tid < 512) {
            int r = tid >> 7;
            float s = 0.f;
#pragma unroll
            for (int c = 0; c < 16; ++c) s += sm.g.pS[c][r][d];
            aggS[r][d] = s;
        }
        __syncthreads();
        // gate halves: gg[0] = u @ WgA, gg[1] = agg @ WgB
        {
            const float* W = Wg + l * (2 * DD * DD) + (halfq ? DD * DD : 0);
            gg[halfq][rq][d] = dotW2(W, halfq ? aggS[rq] : uS[rq], d);
        }
        __syncthreads();
        if (tid < 512) {
            int r = tid >> 7;
            float g = 1.f / (1.f + __expf(-(gg[0][r][d] + gg[1][r][d] + bg[l * DD + d])));
            float nh = fmaf(g, aggS[r][d], hS[r][d]);
            hS[r][d] = nh > 0.f ? nh : 0.f;
        }
        __syncthreads();
        // next-layer u/v GEMM, or classifier head at l==2
        {
            const float* W2 = (l < 2) ? ((halfq ? Wv : Wu) + (l + 1) * DD * DD)
                                      : (Wc1 + (halfq ? DD * DD : 0));
            float acc = dotW2(W2, hS[rq], d);
            if (l < 2) {
                if (!halfq) uS[rq][d] = acc + bu[(l + 1) * DD + d];
                else        scstore(&vout[(size_t)(row0 + rq) * DD + d], acc + bv[(l + 1) * DD + d]);
            } else {
                float val = acc + (halfq ? 0.f : bc1[d]);
                scstore(&(halfq ? hj : hi)[(size_t)(row0 + rq) * DD + d], val);
                float p = val * Wc2[d];
#pragma unroll
                for (int off = 32; off; off >>= 1) p += __shfl_down(p, off);
                if ((tid & 63) == 0) sred[halfq][rq][(tid >> 6) & 1] = p;
            }
        }
        if (l == 2) {
            __syncthreads();
            if (tid < 4) scstore(&S1[row0 + tid], sred[0][tid][0] + sred[0][tid][1]);
            else if (tid < 8) scstore(&S2[row0 + tid - 4], sred[1][tid - 4][0] + sred[1][tid - 4][1]);
        }
        gridbar(barCnt, ++ep);
    }

    // ---------------- edge classifier: one 64x64 tile per block + loss ----------------
    // r9-proven tail (loads at end — no T14 prefetch: keeps VGPR <= 64 for residency).
    {
        int i0 = (bx >> 4) << 6, j0 = (bx & 15) << 6;
        if (tid < 128) wS[tid] = Wc2[tid];
        for (int e2 = tid; e2 < 2048; e2 += 1024) {
            int r = e2 >> 5, c = (e2 & 31) << 2;
            *(f32x4*)&sm.e.hiS[r][c] = *(const f32x4*)(hi + (size_t)(i0 + r) * DD + c);
            f32x4 jv = *(const f32x4*)(hj + (size_t)(j0 + r) * DD + c);
            float2 j01; j01.x = jv[0]; j01.y = jv[1];
            float2 j23; j23.x = jv[2]; j23.y = jv[3];
            *(float2*)&sm.e.hjS[r][c] = j01;
            *(float2*)&sm.e.hjS[r][c + 2] = j23;
        }
        __syncthreads();
        int ty = tid >> 5, tx = tid & 31;      // strided 2x2: rows (ty,ty+32) x cols (tx,tx+32)
        float a00 = 0.f, a01 = 0.f, a10 = 0.f, a11 = 0.f;
#pragma unroll 4
        for (int hh = 0; hh < DD; hh += 4) {
            f32x4 x0 = *(const f32x4*)&sm.e.hiS[ty][hh];
            f32x4 x1 = *(const f32x4*)&sm.e.hiS[ty + 32][hh];
            float2 y0a = *(const float2*)&sm.e.hjS[tx][hh];
            float2 y0b = *(const float2*)&sm.e.hjS[tx][hh + 2];
            float2 y1a = *(const float2*)&sm.e.hjS[tx + 32][hh];
            float2 y1b = *(const float2*)&sm.e.hjS[tx + 32][hh + 2];
            f32x4 w4 = *(const f32x4*)&wS[hh];
            a00 = fmaf(fabsf(x0[0] + y0a.x), w4[0], a00);
            a00 = fmaf(fabsf(x0[1] + y0a.y), w4[1], a00);
            a00 = fmaf(fabsf(x0[2] + y0b.x), w4[2], a00);
            a00 = fmaf(fabsf(x0[3] + y0b.y), w4[3], a00);
            a01 = fmaf(fabsf(x0[0] + y1a.x), w4[0], a01);
            a01 = fmaf(fabsf(x0[1] + y1a.y), w4[1], a01);
            a01 = fmaf(fabsf(x0[2] + y1b.x), w4[2], a01);
            a01 = fmaf(fabsf(x0[3] + y1b.y), w4[3], a01);
            a10 = fmaf(fabsf(x1[0] + y0a.x), w4[0], a10);
            a10 = fmaf(fabsf(x1[1] + y0a.y), w4[1], a10);
            a10 = fmaf(fabsf(x1[2] + y0b.x), w4[2], a10);
            a10 = fmaf(fabsf(x1[3] + y0b.y), w4[3], a10);
            a11 = fmaf(fabsf(x1[0] + y1a.x), w4[0], a11);
            a11 = fmaf(fabsf(x1[1] + y1a.y), w4[1], a11);
            a11 = fmaf(fabsf(x1[2] + y1b.x), w4[2], a11);
            a11 = fmaf(fabsf(x1[3] + y1b.y), w4[3], a11);
        }
        float bcv = bc2[0];
        int ia = i0 + ty, ib = ia + 32, ja = j0 + tx, jb = ja + 32;
        float s1a = S1[ia], s1b = S1[ib];
        float s2a = S2[ja], s2b = S2[jb];
        float lg00 = fmaf(0.5f, a00 + s1a + s2a, bcv);
        float lg01 = fmaf(0.5f, a01 + s1a + s2b, bcv);
        float lg10 = fmaf(0.5f, a10 + s1b + s2a, bcv);
        float lg11 = fmaf(0.5f, a11 + s1b + s2b, bcv);
        size_t o00 = (size_t)ia * NN + ja, o01 = (size_t)ia * NN + jb;
        size_t o10 = (size_t)ib * NN + ja, o11 = (size_t)ib * NN + jb;
        outL[o00] = lg00; outL[o01] = lg01; outL[o10] = lg10; outL[o11] = lg11;
        float t0 = fmaf(lg00, adj[o00], -ew[o00]);
        float t1 = fmaf(lg01, adj[o01], -ew[o01]);
        float t2 = fmaf(lg10, adj[o10], -ew[o10]);
        float t3 = fmaf(lg11, adj[o11], -ew[o11]);
        float ls = fmaf(t0, t0, fmaf(t1, t1, fmaf(t2, t2, t3 * t3)));
#pragma unroll
        for (int off = 32; off; off >>= 1) ls += __shfl_down(ls, off);
        if ((tid & 63) == 0) sm.e.lred[tid >> 6] = ls;
        __syncthreads();
        if (tid == 0) {
            float bls = 0.f;
#pragma unroll
            for (int w = 0; w < 16; ++w) bls += sm.e.lred[w];
            atomicAdd(lossAcc, bls);
            asm volatile("s_waitcnt vmcnt(0)" ::: "memory");
            unsigned old = atomicAdd(counter, 1u);
            if (old == NBLK - 1u) {
                unsigned Lb = __hip_atomic_load((unsigned*)lossAcc,
                                                __ATOMIC_RELAXED, __HIP_MEMORY_SCOPE_AGENT);
                outL[(size_t)NN * NN] = __uint_as_float(Lb) * (1.f / (1024.f * 1024.f));
            }
        }
    }
}

extern "C" void kernel_launch(void* const* d_in, const int* in_sizes, int n_in,
                              void* d_out, int out_size, void* d_ws, size_t ws_size,
                              hipStream_t stream)
{
    const float* nf  = (const float*)d_in[0];
    const float* adj = (const float*)d_in[1];
    const float* ew  = (const float*)d_in[2];
    const float* We  = (const float*)d_in[3];
    const float* be  = (const float*)d_in[4];
    const float* Wu  = (const float*)d_in[5];
    const float* bu  = (const float*)d_in[6];
    const float* Wv  = (const float*)d_in[7];
    const float* bv  = (const float*)d_in[8];
    const float* Wg  = (const float*)d_in[9];
    const float* bg  = (const float*)d_in[10];
    const float* Wc1 = (const float*)d_in[11];
    const float* bc1 = (const float*)d_in[12];
    const float* Wc2 = (const float*)d_in[13];
    const float* bc2 = (const float*)d_in[14];

    float* ws = (float*)d_ws;
    float* vA  = ws;                                 // 131072  (write-once: phase0)
    float* vB  = ws + 131072;                        // 131072  (write-once: layer0)
    float* vC  = ws + 262144;                        // 131072  (write-once: layer1)
    float* hi  = ws + 393216;                        // 131072  (write-once: layer2)
    float* hj  = ws + 524288;                        // 131072  (write-once: layer2)
    float* S1  = ws + 655360;                        // 1024
    float* S2  = ws + 656384;                        // 1024
    float* lossAcc = ws + 657408;                    // 1
    unsigned* counter = (unsigned*)(ws + 657409);    // 1
    unsigned* barCnt = (unsigned*)(ws + 657440);     // 545 uints (sub/master/flag)

    // zero lossAcc + counter + barrier state (capture-legal)
    hipMemsetAsync((void*)lossAcc, 0, 2560, stream);
    k_fused<<<NBLK, 1024, 0, stream>>>(adj, ew, nf, We, be, Wu, bu, Wv, bv, Wg, bg,
                                       Wc1, bc1, Wc2, bc2, vA, vB, vC, hi, hj, S1, S2,
                                       lossAcc, counter, barCnt, (float*)d_out);
}